// Round 1
// baseline (19939.182 us; speedup 1.0000x reference)
//
#include <hip/hip_runtime.h>
#include <hip/hip_bf16.h>
#include <math.h>

#define D 768
#define NH 12
#define DH 64
#define FF 3072
#define NL 12
#define QL 512
#define CL 2048
#define NB 2
#define M_TOT 5120   // 2*512 + 2*2048 tokens, q rows first
#define CHUNKSZ 256
#define WINSZ 256

// ---------------- block-wide reductions (256 threads) ----------------
__device__ __forceinline__ float block_reduce_sum(float v, float* red, int t) {
    red[t] = v; __syncthreads();
    #pragma unroll
    for (int o = 128; o > 0; o >>= 1) {
        if (t < o) red[t] += red[t + o];
        __syncthreads();
    }
    float r = red[0];
    __syncthreads();
    return r;
}

__device__ __forceinline__ float block_reduce_max(float v, float* red, int t) {
    red[t] = v; __syncthreads();
    #pragma unroll
    for (int o = 128; o > 0; o >>= 1) {
        if (t < o) red[t] = fmaxf(red[t], red[t + o]);
        __syncthreads();
    }
    float r = red[0];
    __syncthreads();
    return r;
}

// ---------------- GEMM: C = op(A[M,K] @ W[K,N] + bias[N]) ----------------
// OP: 0 = none, 1 = *0.125 (query scale), 2 = exact gelu
template<int OP>
__global__ __launch_bounds__(256)
void gemm_kernel(const float* __restrict__ A, const float* __restrict__ W,
                 const float* __restrict__ bias, float* __restrict__ C,
                 int M, int N, int K)
{
    __shared__ float As[16][64];      // [k][m]
    __shared__ float Bs[16][68];      // [k][n], padded
    const int tid = threadIdx.x;
    const int tx = tid & 15, ty = tid >> 4;
    const int m0 = blockIdx.x * 64;
    const int n0 = blockIdx.y * 64;

    const int arow = tid >> 2;        // 0..63
    const int ak4  = (tid & 3) * 4;   // 0,4,8,12
    const int brow = tid >> 4;        // 0..15
    const int bn4  = (tid & 15) * 4;  // 0..60

    float acc[4][4] = {};

    for (int k0 = 0; k0 < K; k0 += 16) {
        float4 av = *(const float4*)(A + (size_t)(m0 + arow) * K + k0 + ak4);
        float4 bv = *(const float4*)(W + (size_t)(k0 + brow) * N + n0 + bn4);
        __syncthreads();
        As[ak4 + 0][arow] = av.x;
        As[ak4 + 1][arow] = av.y;
        As[ak4 + 2][arow] = av.z;
        As[ak4 + 3][arow] = av.w;
        *(float4*)&Bs[brow][bn4] = bv;
        __syncthreads();
        #pragma unroll
        for (int kk = 0; kk < 16; ++kk) {
            float a[4], b[4];
            #pragma unroll
            for (int i = 0; i < 4; i++) a[i] = As[kk][ty * 4 + i];
            #pragma unroll
            for (int j = 0; j < 4; j++) b[j] = Bs[kk][tx * 4 + j];
            #pragma unroll
            for (int i = 0; i < 4; i++)
                #pragma unroll
                for (int j = 0; j < 4; j++)
                    acc[i][j] += a[i] * b[j];
        }
    }
    #pragma unroll
    for (int i = 0; i < 4; i++) {
        int m = m0 + ty * 4 + i;
        #pragma unroll
        for (int j = 0; j < 4; j++) {
            int n = n0 + tx * 4 + j;
            float v = acc[i][j] + bias[n];
            if (OP == 1) v *= 0.125f;
            if (OP == 2) v = 0.5f * v * (1.0f + erff(v * 0.70710678118654752f));
            C[(size_t)m * N + n] = v;
        }
    }
}

// ---------------- embedding + LN ----------------
__global__ __launch_bounds__(256)
void embed_kernel(const int* __restrict__ q_ids, const int* __restrict__ c_ids,
                  const float* __restrict__ we, const float* __restrict__ pe,
                  const float* __restrict__ te,
                  const float* __restrict__ g, const float* __restrict__ bp,
                  float* __restrict__ hbuf)
{
    __shared__ float red[256];
    int row = blockIdx.x;
    int id, s;
    if (row < NB * QL) { int b = row / QL; s = row % QL; id = q_ids[b * QL + s]; }
    else { int r = row - NB * QL; int b = r / CL; s = r % CL; id = c_ids[b * CL + s]; }
    int t = threadIdx.x;
    float x[3];
    float sum = 0.f;
    #pragma unroll
    for (int i = 0; i < 3; i++) {
        int d = t + i * 256;
        x[i] = we[(size_t)id * D + d] + pe[(size_t)s * D + d] + te[d];
        sum += x[i];
    }
    float mean = block_reduce_sum(sum, red, t) * (1.0f / D);
    float vs = 0.f;
    #pragma unroll
    for (int i = 0; i < 3; i++) { float dv = x[i] - mean; vs += dv * dv; }
    float var = block_reduce_sum(vs, red, t) * (1.0f / D);
    float rstd = rsqrtf(var + 1e-12f);
    #pragma unroll
    for (int i = 0; i < 3; i++) {
        int d = t + i * 256;
        hbuf[(size_t)row * D + d] = (x[i] - mean) * rstd * g[d] + bp[d];
    }
}

// ---------------- residual add + LN (in place on hbuf) ----------------
__global__ __launch_bounds__(256)
void add_ln_kernel(float* __restrict__ hbuf, const float* __restrict__ delta,
                   const float* __restrict__ g, const float* __restrict__ bp)
{
    __shared__ float red[256];
    int row = blockIdx.x;
    int t = threadIdx.x;
    float x[3];
    float sum = 0.f;
    #pragma unroll
    for (int i = 0; i < 3; i++) {
        int d = t + i * 256;
        x[i] = hbuf[(size_t)row * D + d] + delta[(size_t)row * D + d];
        sum += x[i];
    }
    float mean = block_reduce_sum(sum, red, t) * (1.0f / D);
    float vs = 0.f;
    #pragma unroll
    for (int i = 0; i < 3; i++) { float dv = x[i] - mean; vs += dv * dv; }
    float var = block_reduce_sum(vs, red, t) * (1.0f / D);
    float rstd = rsqrtf(var + 1e-12f);
    #pragma unroll
    for (int i = 0; i < 3; i++) {
        int d = t + i * 256;
        hbuf[(size_t)row * D + d] = (x[i] - mean) * rstd * g[d] + bp[d];
    }
}

// ---------------- sliding-window attention ----------------
// grid.x = 20 chunks (4 q-chunks then 16 c-chunks), grid.y = 12 heads
// block = 256 threads, thread qi owns query row qi of the chunk.
__global__ __launch_bounds__(256)
void attn_kernel(const float* __restrict__ Qb, const float* __restrict__ Kb,
                 const float* __restrict__ Vb, const int* __restrict__ mq,
                 const int* __restrict__ mc, float* __restrict__ Ao)
{
    __shared__ float Ks[64][DH];
    __shared__ float Vs[64][DH];
    __shared__ float smask[64];

    int cg = blockIdx.x;
    int head = blockIdx.y;
    int base, n, nc;
    const int* mask;
    if (cg < 4) {            // q sequences: nc = 2 chunks each
        int b = cg >> 1; n = cg & 1; nc = QL / CHUNKSZ;
        base = b * QL; mask = mq + b * QL;
    } else {                 // c sequences: nc = 8 chunks each
        int tt = cg - 4; int b = tt >> 3; n = tt & 7; nc = CL / CHUNKSZ;
        base = NB * QL + b * CL; mask = mc + b * CL;
    }
    const int qi = threadIdx.x;
    const int row = base + n * CHUNKSZ + qi;

    float q[DH];
    const float* qp = Qb + (size_t)row * D + head * DH;
    #pragma unroll
    for (int d = 0; d < DH; d += 4) {
        float4 v = *(const float4*)(qp + d);
        q[d] = v.x; q[d+1] = v.y; q[d+2] = v.z; q[d+3] = v.w;
    }

    float m = -1e30f, l = 0.f;
    float acc[DH] = {};

    for (int co = 0; co < 3; ++co) {
        int cidx = n - 1 + co;
        if (cidx < 0 || cidx >= nc) continue;   // zero-pad chunk: fully masked
        for (int t4 = 0; t4 < 4; ++t4) {
            int ki = threadIdx.x >> 2;
            int dg = (threadIdx.x & 3) * 16;
            int krow = base + cidx * CHUNKSZ + t4 * 64 + ki;
            const float* kp = Kb + (size_t)krow * D + head * DH + dg;
            const float* vp = Vb + (size_t)krow * D + head * DH + dg;
            __syncthreads();
            #pragma unroll
            for (int d = 0; d < 16; d += 4) {
                *(float4*)&Ks[ki][dg + d] = *(const float4*)(kp + d);
                *(float4*)&Vs[ki][dg + d] = *(const float4*)(vp + d);
            }
            if (threadIdx.x < 64)
                smask[threadIdx.x] = (float)mask[cidx * CHUNKSZ + t4 * 64 + threadIdx.x];
            __syncthreads();
            int pbase = co * CHUNKSZ + t4 * 64;      // position in the 3c window
            for (int kk = 0; kk < 64; ++kk) {
                float s = 0.f;
                #pragma unroll
                for (int d = 0; d < DH; ++d) s += q[d] * Ks[kk][d];
                int rel = pbase + kk - CHUNKSZ - qi;
                bool valid = (rel >= -WINSZ) && (rel <= WINSZ) && (smask[kk] > 0.f);
                float snew = valid ? s : -1e30f;
                float mnew = fmaxf(m, snew);
                float alpha = __expf(m - mnew);
                float p = valid ? __expf(s - mnew) : 0.f;
                l = l * alpha + p;
                #pragma unroll
                for (int d = 0; d < DH; ++d) acc[d] = acc[d] * alpha + p * Vs[kk][d];
                m = mnew;
            }
        }
    }
    float inv = (l > 0.f) ? 1.f / l : 0.f;
    float* op = Ao + (size_t)row * D + head * DH;
    #pragma unroll
    for (int d = 0; d < DH; d += 4) {
        float4 v; v.x = acc[d]*inv; v.y = acc[d+1]*inv; v.z = acc[d+2]*inv; v.w = acc[d+3]*inv;
        *(float4*)(op + d) = v;
    }
}

// ---------------- interaction: scores + row softmax ----------------
// grid: (CL, NB); block 256; thread t handles q columns t and t+256
__global__ __launch_bounds__(256)
void inter_scores_kernel(const float* __restrict__ hbuf, float* __restrict__ probs)
{
    __shared__ float cs[D];
    __shared__ float red[256];
    int b = blockIdx.y;
    int ci = blockIdx.x;
    const float* crow = hbuf + (size_t)(NB * QL + b * CL + ci) * D;
    int t = threadIdx.x;
    #pragma unroll
    for (int i = 0; i < 3; i++) cs[t + i * 256] = crow[t + i * 256];
    __syncthreads();
    const float* q0 = hbuf + (size_t)(b * QL + t) * D;
    const float* q1 = hbuf + (size_t)(b * QL + t + 256) * D;
    float s0 = 0.f, s1 = 0.f;
    for (int d = 0; d < D; d += 4) {
        float4 a = *(const float4*)(cs + d);
        float4 u = *(const float4*)(q0 + d);
        float4 v = *(const float4*)(q1 + d);
        s0 += a.x*u.x + a.y*u.y + a.z*u.z + a.w*u.w;
        s1 += a.x*v.x + a.y*v.y + a.z*v.z + a.w*v.w;
    }
    float mx = block_reduce_max(fmaxf(s0, s1), red, t);
    float e0 = __expf(s0 - mx), e1 = __expf(s1 - mx);
    float ssum = block_reduce_sum(e0 + e1, red, t);
    float inv = 1.f / ssum;
    float* pr = probs + ((size_t)b * CL + ci) * QL;
    pr[t] = e0 * inv;
    pr[t + 256] = e1 * inv;
}

// ---------------- column max over c axis ----------------
__global__ __launch_bounds__(256)
void colmax_kernel(const float* __restrict__ probs, float* __restrict__ mout)
{
    int j = blockIdx.x * 256 + threadIdx.x;   // 0..1023 -> (b, q)
    int b = j >> 9, qcol = j & 511;
    const float* p = probs + (size_t)b * CL * QL + qcol;
    float mx = -1e30f;
    for (int i = 0; i < CL; i++) mx = fmaxf(mx, p[(size_t)i * QL]);
    mout[j] = mx;
}

// ---------------- final fc: out[b,o] = m[b,:] @ fc_w[:,o] + fc_b[o] ----------------
__global__ __launch_bounds__(256)
void fc_kernel(const float* __restrict__ mout, const float* __restrict__ fcw,
               const float* __restrict__ fcb, float* __restrict__ out)
{
    __shared__ float red[256];
    int t = threadIdx.x;
    for (int b = 0; b < NB; b++) {
        for (int o = 0; o < 4; o++) {
            float s = 0.f;
            for (int j = t; j < QL; j += 256) s += mout[b * QL + j] * fcw[j * 4 + o];
            float tot = block_reduce_sum(s, red, t);
            if (t == 0) out[b * 4 + o] = tot + fcb[o];
            __syncthreads();
        }
    }
}

extern "C" void kernel_launch(void* const* d_in, const int* in_sizes, int n_in,
                              void* d_out, int out_size, void* d_ws, size_t ws_size,
                              hipStream_t stream)
{
    (void)in_sizes; (void)n_in; (void)out_size; (void)ws_size;
    const int*   q_ids  = (const int*)d_in[0];
    const int*   c_ids  = (const int*)d_in[1];
    const int*   q_mask = (const int*)d_in[2];
    const int*   c_mask = (const int*)d_in[3];
    const float* we  = (const float*)d_in[4];
    const float* pe  = (const float*)d_in[5];
    const float* te  = (const float*)d_in[6];
    const float* eg  = (const float*)d_in[7];
    const float* ebp = (const float*)d_in[8];
    const float* Wq  = (const float*)d_in[9];
    const float* bq  = (const float*)d_in[10];
    const float* Wk  = (const float*)d_in[11];
    const float* bk  = (const float*)d_in[12];
    const float* Wv  = (const float*)d_in[13];
    const float* bv  = (const float*)d_in[14];
    const float* Wo  = (const float*)d_in[15];
    const float* bo  = (const float*)d_in[16];
    const float* g1  = (const float*)d_in[17];
    const float* be1 = (const float*)d_in[18];
    const float* W1  = (const float*)d_in[19];
    const float* bf1 = (const float*)d_in[20];
    const float* W2  = (const float*)d_in[21];
    const float* bf2 = (const float*)d_in[22];
    const float* g2  = (const float*)d_in[23];
    const float* be2 = (const float*)d_in[24];
    const float* fcw = (const float*)d_in[25];
    const float* fcb = (const float*)d_in[26];

    float* ws = (float*)d_ws;
    const size_t SZ = (size_t)M_TOT * D;      // 3,932,160 floats
    float* h    = ws;
    float* bufA = h    + SZ;   // q  / F1 part 0 / probs
    float* bufB = bufA + SZ;   // k  / F1 part 1
    float* bufC = bufB + SZ;   // v  / F1 part 2
    float* bufD = bufC + SZ;   // attn out / F1 part 3
    float* bufE = bufD + SZ;   // gemm delta (O / F2)
    float* tail = bufE + SZ;   // colmax result [NB*QL]

    embed_kernel<<<M_TOT, 256, 0, stream>>>(q_ids, c_ids, we, pe, te, eg, ebp, h);

    for (int l = 0; l < NL; ++l) {
        const size_t wofD = (size_t)l * D * D;
        gemm_kernel<1><<<dim3(M_TOT/64, D/64), 256, 0, stream>>>(h, Wq + wofD, bq + l * D, bufA, M_TOT, D, D);
        gemm_kernel<0><<<dim3(M_TOT/64, D/64), 256, 0, stream>>>(h, Wk + wofD, bk + l * D, bufB, M_TOT, D, D);
        gemm_kernel<0><<<dim3(M_TOT/64, D/64), 256, 0, stream>>>(h, Wv + wofD, bv + l * D, bufC, M_TOT, D, D);
        attn_kernel<<<dim3(20, NH), 256, 0, stream>>>(bufA, bufB, bufC, q_mask, c_mask, bufD);
        gemm_kernel<0><<<dim3(M_TOT/64, D/64), 256, 0, stream>>>(bufD, Wo + wofD, bo + l * D, bufE, M_TOT, D, D);
        add_ln_kernel<<<M_TOT, 256, 0, stream>>>(h, bufE, g1 + l * D, be1 + l * D);
        gemm_kernel<2><<<dim3(M_TOT/64, FF/64), 256, 0, stream>>>(h, W1 + (size_t)l * D * FF, bf1 + l * FF, bufA, M_TOT, FF, D);
        gemm_kernel<0><<<dim3(M_TOT/64, D/64), 256, 0, stream>>>(bufA, W2 + (size_t)l * FF * D, bf2 + l * D, bufE, M_TOT, D, FF);
        add_ln_kernel<<<M_TOT, 256, 0, stream>>>(h, bufE, g2 + l * D, be2 + l * D);
    }

    float* probs = bufA;   // [NB, CL, QL] = 2,097,152 floats < SZ
    inter_scores_kernel<<<dim3(CL, NB), 256, 0, stream>>>(h, probs);
    colmax_kernel<<<dim3((NB * QL) / 256), 256, 0, stream>>>(probs, tail);
    fc_kernel<<<1, 256, 0, stream>>>(tail, fcw, fcb, (float*)d_out);
}

// Round 2
// 6938.029 us; speedup vs baseline: 2.8739x; 2.8739x over previous
//
#include <hip/hip_runtime.h>
#include <math.h>

#define D 768
#define NH 12
#define DH 64
#define FF 3072
#define NL 12
#define QL 512
#define CL 2048
#define NB 2
#define M_TOT 5120   // 2*512 + 2*2048 tokens, q rows first
#define CHUNKSZ 256
#define WINSZ 256
#define QSTR 2304    // fused QKV row stride

typedef short bf16x8 __attribute__((ext_vector_type(8)));
typedef float f32x4 __attribute__((ext_vector_type(4)));

__device__ __forceinline__ short f2bf(float x) {
    union { float f; unsigned u; } v; v.f = x;
    unsigned r = v.u + 0x7fffu + ((v.u >> 16) & 1u);   // round-to-nearest-even
    return (short)(r >> 16);
}

#define GLD16(gp, lp) __builtin_amdgcn_global_load_lds( \
    (const __attribute__((address_space(1))) unsigned int*)(gp), \
    (__attribute__((address_space(3))) unsigned int*)(lp), 16, 0, 0)

// ---------------- block-wide reductions (256 threads) ----------------
__device__ __forceinline__ float block_reduce_sum(float v, float* red, int t) {
    red[t] = v; __syncthreads();
    #pragma unroll
    for (int o = 128; o > 0; o >>= 1) {
        if (t < o) red[t] += red[t + o];
        __syncthreads();
    }
    float r = red[0];
    __syncthreads();
    return r;
}

__device__ __forceinline__ float block_reduce_max(float v, float* red, int t) {
    red[t] = v; __syncthreads();
    #pragma unroll
    for (int o = 128; o > 0; o >>= 1) {
        if (t < o) red[t] = fmaxf(red[t], red[t + o]);
        __syncthreads();
    }
    float r = red[0];
    __syncthreads();
    return r;
}

// ---------------- MFMA GEMM: C = op(A[M,K] @ Bt[N,K]^T + bias) ----------------
// A, Bt bf16 row-major; 128x128 tile, BK=32, 4 waves each 64x64 (4x4 frags of 16x16x32)
// OP: 0 none, 2 exact gelu. WF32: write fp32 to Cf (stride ldc). WBF16: write bf16 to Cb (stride N).
template<int OP, int WF32, int WBF16>
__global__ __launch_bounds__(256)
void mfma_gemm(const short* __restrict__ A, const short* __restrict__ Bt,
               const float* __restrict__ bias, float* __restrict__ Cf,
               short* __restrict__ Cb, int M, int N, int K, int ldc,
               long aZ, long btZ, long cZ)
{
    __shared__ short As[128 * 32];
    __shared__ short Bs[128 * 32];
    const int tid = threadIdx.x;
    const int wave = tid >> 6, lane = tid & 63;
    const int m0 = blockIdx.x * 128, n0 = blockIdx.y * 128;
    const int wm = (wave >> 1) * 64, wn = (wave & 1) * 64;
    A  += (size_t)blockIdx.z * aZ;
    Bt += (size_t)blockIdx.z * btZ;

    // staging: 512 chunks of 16B; chunk idx -> row = idx>>2, koff = (idx&3)*8
    const int srow = tid >> 2;
    const int skg  = (tid & 3) << 3;
    const short* gA = A  + (size_t)(m0 + srow) * K + skg;
    const short* gB = Bt + (size_t)(n0 + srow) * K + skg;

    f32x4 acc[4][4] = {};
    const int lrow = lane & 15;
    const int lk   = (lane >> 4) << 3;

    for (int k0 = 0; k0 < K; k0 += 32) {
        if (k0) __syncthreads();
        GLD16(gA + k0,                 As + tid * 8);
        GLD16(gA + k0 + (size_t)64*K,  As + (tid + 256) * 8);
        GLD16(gB + k0,                 Bs + tid * 8);
        GLD16(gB + k0 + (size_t)64*K,  Bs + (tid + 256) * 8);
        __syncthreads();
        bf16x8 af[4], bfv[4];
        #pragma unroll
        for (int i = 0; i < 4; i++) af[i]  = *(const bf16x8*)(As + (wm + i*16 + lrow)*32 + lk);
        #pragma unroll
        for (int j = 0; j < 4; j++) bfv[j] = *(const bf16x8*)(Bs + (wn + j*16 + lrow)*32 + lk);
        #pragma unroll
        for (int i = 0; i < 4; i++)
            #pragma unroll
            for (int j = 0; j < 4; j++)
                acc[i][j] = __builtin_amdgcn_mfma_f32_16x16x32_bf16(af[i], bfv[j], acc[i][j], 0, 0, 0);
    }

    const int cn = lane & 15;
    const int rq = (lane >> 4) << 2;
    #pragma unroll
    for (int j = 0; j < 4; j++) {
        int n = n0 + wn + j * 16 + cn;
        float bv = bias ? bias[n] : 0.f;
        #pragma unroll
        for (int i = 0; i < 4; i++) {
            #pragma unroll
            for (int r2 = 0; r2 < 4; r2++) {
                int m = m0 + wm + i * 16 + rq + r2;
                float v = acc[i][j][r2] + bv;
                if (OP == 2) v = 0.5f * v * (1.0f + erff(v * 0.70710678118654752f));
                if (WF32)  Cf[(size_t)blockIdx.z * cZ + (size_t)m * ldc + n] = v;
                if (WBF16) Cb[(size_t)m * N + n] = f2bf(v);
            }
        }
    }
}

// ---------------- weight transpose + bf16 convert ----------------
// 4x D x D mats: Wq (scaled 0.125) -> WtQKV rows 0..767, Wk -> 768.., Wv -> 1536.., Wo -> WtO
__global__ __launch_bounds__(256)
void conv_qkvo(const float* __restrict__ Wq, const float* __restrict__ Wk,
               const float* __restrict__ Wv, const float* __restrict__ Wo,
               short* __restrict__ WtQKV, short* __restrict__ WtO)
{
    __shared__ float tl[32][33];
    int z = blockIdx.z;
    const float* src = (z == 0) ? Wq : (z == 1) ? Wk : (z == 2) ? Wv : Wo;
    float scale = (z == 0) ? 0.125f : 1.0f;
    short* dst = (z < 3) ? (WtQKV + (size_t)z * D * D) : WtO;
    int r0 = blockIdx.y * 32, c0 = blockIdx.x * 32;
    int tx = threadIdx.x & 31, ty = threadIdx.x >> 5;
    #pragma unroll
    for (int i = 0; i < 4; i++)
        tl[ty + 8*i][tx] = src[(size_t)(r0 + ty + 8*i) * D + c0 + tx] * scale;
    __syncthreads();
    #pragma unroll
    for (int i = 0; i < 4; i++)
        dst[(size_t)(c0 + ty + 8*i) * D + r0 + tx] = f2bf(tl[tx][ty + 8*i]);
}

__global__ __launch_bounds__(256)
void transpose_bf(const float* __restrict__ in, short* __restrict__ out, int R, int C)
{
    __shared__ float tl[32][33];
    int r0 = blockIdx.y * 32, c0 = blockIdx.x * 32;
    int tx = threadIdx.x & 31, ty = threadIdx.x >> 5;
    #pragma unroll
    for (int i = 0; i < 4; i++)
        tl[ty + 8*i][tx] = in[(size_t)(r0 + ty + 8*i) * C + c0 + tx];
    __syncthreads();
    #pragma unroll
    for (int i = 0; i < 4; i++)
        out[(size_t)(c0 + ty + 8*i) * R + r0 + tx] = f2bf(tl[tx][ty + 8*i]);
}

__global__ __launch_bounds__(256)
void bias_cat(const float* __restrict__ bq, const float* __restrict__ bk,
              const float* __restrict__ bv, float* __restrict__ ob)
{
    int i = blockIdx.x * 256 + threadIdx.x;
    if (i >= QSTR) return;
    if (i < D) ob[i] = bq[i] * 0.125f;
    else if (i < 2 * D) ob[i] = bk[i - D];
    else ob[i] = bv[i - 2 * D];
}

// ---------------- embedding + LN (writes fp32 h and bf16 copy) ----------------
__global__ __launch_bounds__(256)
void embed_kernel(const int* __restrict__ q_ids, const int* __restrict__ c_ids,
                  const float* __restrict__ we, const float* __restrict__ pe,
                  const float* __restrict__ te,
                  const float* __restrict__ g, const float* __restrict__ bp,
                  float* __restrict__ hbuf, short* __restrict__ hb)
{
    __shared__ float red[256];
    int row = blockIdx.x;
    int id, s;
    if (row < NB * QL) { int b = row / QL; s = row % QL; id = q_ids[b * QL + s]; }
    else { int r = row - NB * QL; int b = r / CL; s = r % CL; id = c_ids[b * CL + s]; }
    int t = threadIdx.x;
    float x[3];
    float sum = 0.f;
    #pragma unroll
    for (int i = 0; i < 3; i++) {
        int d = t + i * 256;
        x[i] = we[(size_t)id * D + d] + pe[(size_t)s * D + d] + te[d];
        sum += x[i];
    }
    float mean = block_reduce_sum(sum, red, t) * (1.0f / D);
    float vs = 0.f;
    #pragma unroll
    for (int i = 0; i < 3; i++) { float dv = x[i] - mean; vs += dv * dv; }
    float var = block_reduce_sum(vs, red, t) * (1.0f / D);
    float rstd = rsqrtf(var + 1e-12f);
    #pragma unroll
    for (int i = 0; i < 3; i++) {
        int d = t + i * 256;
        float y = (x[i] - mean) * rstd * g[d] + bp[d];
        hbuf[(size_t)row * D + d] = y;
        hb[(size_t)row * D + d] = f2bf(y);
    }
}

// ---------------- residual add + LN (in place, writes fp32 + bf16) ----------------
__global__ __launch_bounds__(256)
void add_ln_kernel(float* __restrict__ hbuf, const float* __restrict__ delta,
                   const float* __restrict__ g, const float* __restrict__ bp,
                   short* __restrict__ hb)
{
    __shared__ float red[256];
    int row = blockIdx.x;
    int t = threadIdx.x;
    float x[3];
    float sum = 0.f;
    #pragma unroll
    for (int i = 0; i < 3; i++) {
        int d = t + i * 256;
        x[i] = hbuf[(size_t)row * D + d] + delta[(size_t)row * D + d];
        sum += x[i];
    }
    float mean = block_reduce_sum(sum, red, t) * (1.0f / D);
    float vs = 0.f;
    #pragma unroll
    for (int i = 0; i < 3; i++) { float dv = x[i] - mean; vs += dv * dv; }
    float var = block_reduce_sum(vs, red, t) * (1.0f / D);
    float rstd = rsqrtf(var + 1e-12f);
    #pragma unroll
    for (int i = 0; i < 3; i++) {
        int d = t + i * 256;
        float y = (x[i] - mean) * rstd * g[d] + bp[d];
        hbuf[(size_t)row * D + d] = y;
        hb[(size_t)row * D + d] = f2bf(y);
    }
}

// ---------------- sliding-window attention (fp32, 4 lanes per q-row) ----------------
// grid.x = 80 (20 chunks x 4 row-groups), grid.y = 12 heads; 256 threads = 64 rows x 4 lanes
__global__ __launch_bounds__(256)
void attn_kernel(const float* __restrict__ QKV, const int* __restrict__ mq,
                 const int* __restrict__ mc, short* __restrict__ Ao)
{
    __shared__ float Ks[64][68];
    __shared__ float Vs[64][68];
    __shared__ float smask[64];

    int bx = blockIdx.x;
    int cg = bx >> 2, rg = bx & 3;
    int head = blockIdx.y;
    int base, n, nc;
    const int* mask;
    if (cg < 4) { int b = cg >> 1; n = cg & 1; nc = QL / CHUNKSZ; base = b * QL; mask = mq + b * QL; }
    else { int t2 = cg - 4; int b = t2 >> 3; n = t2 & 7; nc = CL / CHUNKSZ; base = NB * QL + b * CL; mask = mc + b * CL; }

    const int tid = threadIdx.x;
    const int r = tid >> 2, g = tid & 3;
    const int qi = rg * 64 + r;
    const int row = base + n * CHUNKSZ + qi;

    float q16[16];
    const float* qp = QKV + (size_t)row * QSTR + head * DH + g * 16;
    #pragma unroll
    for (int d = 0; d < 16; d += 4) {
        float4 v = *(const float4*)(qp + d);
        q16[d] = v.x; q16[d+1] = v.y; q16[d+2] = v.z; q16[d+3] = v.w;
    }

    float m = -1e30f, l = 0.f;
    float acc[16] = {};

    const int ki = tid >> 2, dg2 = (tid & 3) * 16;
    for (int co = 0; co < 3; ++co) {
        int cidx = n - 1 + co;
        if (cidx < 0 || cidx >= nc) continue;
        for (int t4 = 0; t4 < 4; ++t4) {
            int krow = base + cidx * CHUNKSZ + t4 * 64 + ki;
            const float* kp = QKV + (size_t)krow * QSTR + D + head * DH + dg2;
            const float* vp = QKV + (size_t)krow * QSTR + 2 * D + head * DH + dg2;
            __syncthreads();
            #pragma unroll
            for (int d = 0; d < 16; d += 4) {
                *(float4*)&Ks[ki][dg2 + d] = *(const float4*)(kp + d);
                *(float4*)&Vs[ki][dg2 + d] = *(const float4*)(vp + d);
            }
            if (tid < 64)
                smask[tid] = (float)mask[cidx * CHUNKSZ + t4 * 64 + tid];
            __syncthreads();
            int pbase = co * CHUNKSZ + t4 * 64;
            for (int kk = 0; kk < 64; ++kk) {
                float s = 0.f;
                #pragma unroll
                for (int d = 0; d < 16; d += 4) {
                    float4 kv = *(const float4*)&Ks[kk][g * 16 + d];
                    s += q16[d] * kv.x + q16[d+1] * kv.y + q16[d+2] * kv.z + q16[d+3] * kv.w;
                }
                s += __shfl_xor(s, 1);
                s += __shfl_xor(s, 2);
                int rel = pbase + kk - CHUNKSZ - qi;
                bool valid = (rel >= -WINSZ) && (rel <= WINSZ) && (smask[kk] > 0.f);
                float sv = valid ? s : -1e30f;
                float mnew = fmaxf(m, sv);
                float alpha = __expf(m - mnew);
                float p = valid ? __expf(s - mnew) : 0.f;
                l = l * alpha + p;
                #pragma unroll
                for (int d = 0; d < 16; d += 4) {
                    float4 vv = *(const float4*)&Vs[kk][g * 16 + d];
                    acc[d]   = acc[d]   * alpha + p * vv.x;
                    acc[d+1] = acc[d+1] * alpha + p * vv.y;
                    acc[d+2] = acc[d+2] * alpha + p * vv.z;
                    acc[d+3] = acc[d+3] * alpha + p * vv.w;
                }
                m = mnew;
            }
        }
    }
    float inv = (l > 0.f) ? 1.f / l : 0.f;
    short* op = Ao + (size_t)row * D + head * DH + g * 16;
    #pragma unroll
    for (int d = 0; d < 16; d++) op[d] = f2bf(acc[d] * inv);
}

// ---------------- interaction softmax over q axis (in place) ----------------
__global__ __launch_bounds__(256)
void inter_softmax(float* __restrict__ scores)
{
    __shared__ float red[256];
    int t = threadIdx.x;
    float* rowp = scores + ((size_t)blockIdx.y * CL + blockIdx.x) * QL;
    float s0 = rowp[t], s1 = rowp[t + 256];
    float mx = block_reduce_max(fmaxf(s0, s1), red, t);
    float e0 = __expf(s0 - mx), e1 = __expf(s1 - mx);
    float ssum = block_reduce_sum(e0 + e1, red, t);
    float inv = 1.f / ssum;
    rowp[t] = e0 * inv;
    rowp[t + 256] = e1 * inv;
}

// ---------------- column max over c axis, 2-stage ----------------
__global__ __launch_bounds__(256)
void colmax_part(const float* __restrict__ probs, float* __restrict__ part)
{
    int j = blockIdx.x * 256 + threadIdx.x;   // 0..1023 -> (b, q)
    int b = j >> 9, q = j & 511;
    const float* p = probs + (size_t)b * CL * QL + q;
    int i0 = blockIdx.y * 128;
    float mx = -1e30f;
    for (int i = 0; i < 128; i++) mx = fmaxf(mx, p[(size_t)(i0 + i) * QL]);
    part[blockIdx.y * 1024 + j] = mx;
}

__global__ __launch_bounds__(256)
void colmax_fin(const float* __restrict__ part, float* __restrict__ tail)
{
    int j = blockIdx.x * 256 + threadIdx.x;
    float mx = -1e30f;
    #pragma unroll
    for (int y = 0; y < 16; y++) mx = fmaxf(mx, part[y * 1024 + j]);
    tail[j] = mx;
}

// ---------------- final fc ----------------
__global__ __launch_bounds__(256)
void fc_kernel(const float* __restrict__ mout, const float* __restrict__ fcw,
               const float* __restrict__ fcb, float* __restrict__ out)
{
    __shared__ float red[256];
    int t = threadIdx.x;
    for (int b = 0; b < NB; b++) {
        for (int o = 0; o < 4; o++) {
            float s = 0.f;
            for (int j = t; j < QL; j += 256) s += mout[b * QL + j] * fcw[j * 4 + o];
            float tot = block_reduce_sum(s, red, t);
            if (t == 0) out[b * 4 + o] = tot + fcb[o];
            __syncthreads();
        }
    }
}

extern "C" void kernel_launch(void* const* d_in, const int* in_sizes, int n_in,
                              void* d_out, int out_size, void* d_ws, size_t ws_size,
                              hipStream_t stream)
{
    (void)in_sizes; (void)n_in; (void)out_size; (void)ws_size;
    const int*   q_ids  = (const int*)d_in[0];
    const int*   c_ids  = (const int*)d_in[1];
    const int*   q_mask = (const int*)d_in[2];
    const int*   c_mask = (const int*)d_in[3];
    const float* we  = (const float*)d_in[4];
    const float* pe  = (const float*)d_in[5];
    const float* te  = (const float*)d_in[6];
    const float* eg  = (const float*)d_in[7];
    const float* ebp = (const float*)d_in[8];
    const float* Wq  = (const float*)d_in[9];
    const float* bq  = (const float*)d_in[10];
    const float* Wk  = (const float*)d_in[11];
    const float* bk  = (const float*)d_in[12];
    const float* Wv  = (const float*)d_in[13];
    const float* bv  = (const float*)d_in[14];
    const float* Wo  = (const float*)d_in[15];
    const float* bo  = (const float*)d_in[16];
    const float* g1  = (const float*)d_in[17];
    const float* be1 = (const float*)d_in[18];
    const float* W1  = (const float*)d_in[19];
    const float* bf1 = (const float*)d_in[20];
    const float* W2  = (const float*)d_in[21];
    const float* bf2 = (const float*)d_in[22];
    const float* g2  = (const float*)d_in[23];
    const float* be2 = (const float*)d_in[24];
    const float* fcw = (const float*)d_in[25];
    const float* fcb = (const float*)d_in[26];

    const size_t SZ    = (size_t)M_TOT * D;       //  3,932,160 f
    const size_t QKVSZ = (size_t)M_TOT * QSTR;    // 11,796,480 f
    const size_t WTEL  = (size_t)QSTR * D + (size_t)D * D + 2 * (size_t)D * FF; // 7,077,888 el

    float* ws      = (float*)d_ws;
    float* h       = ws;                                   // fp32 [M_TOT, D]
    short* h_bf    = (short*)(h + SZ);                     // bf16 [M_TOT, D]
    float* QKVbuf  = h + SZ + SZ / 2;                      // fp32 [M_TOT, 2304]
    short* attnout = (short*)(QKVbuf + QKVSZ);             // bf16 [M_TOT, D]
    short* Wt      = (short*)(QKVbuf + QKVSZ + SZ / 2);    // per-layer weights bf16
    float* misc    = (float*)(Wt + WTEL);
    float* qkvbias = misc;                                 // [2304]
    float* part    = misc + QSTR;                          // [16*1024]
    float* tail    = part + 16384;                         // [1024]

    short* WtQKV   = Wt;                                   // [2304, 768]
    short* WtO     = Wt + (size_t)QSTR * D;                // [768, 768]
    short* Wt1     = WtO + (size_t)D * D;                  // [3072, 768]
    short* Wt2     = Wt1 + (size_t)D * FF;                 // [768, 3072]

    short* ffn1_bf = (short*)QKVbuf;                       // bf16 [M_TOT, FF] (aliases QKV)
    float* deltaF  = QKVbuf + SZ * 2;                      // fp32 [M_TOT, D] (aliases QKV tail)
    float* scores  = QKVbuf;                               // fp32 [NB, CL, QL] (aliases QKV)

    embed_kernel<<<M_TOT, 256, 0, stream>>>(q_ids, c_ids, we, pe, te, eg, ebp, h, h_bf);

    for (int l = 0; l < NL; ++l) {
        const size_t oDD = (size_t)l * D * D;
        const size_t oDF = (size_t)l * D * FF;
        conv_qkvo<<<dim3(24, 24, 4), 256, 0, stream>>>(Wq + oDD, Wk + oDD, Wv + oDD, Wo + oDD, WtQKV, WtO);
        transpose_bf<<<dim3(FF/32, D/32), 256, 0, stream>>>(W1 + oDF, Wt1, D, FF);
        transpose_bf<<<dim3(D/32, FF/32), 256, 0, stream>>>(W2 + oDF, Wt2, FF, D);
        bias_cat<<<9, 256, 0, stream>>>(bq + (size_t)l * D, bk + (size_t)l * D, bv + (size_t)l * D, qkvbias);

        // fused QKV: [M_TOT, 768] @ [2304, 768]^T -> fp32 [M_TOT, 2304]
        mfma_gemm<0,1,0><<<dim3(M_TOT/128, QSTR/128), 256, 0, stream>>>(
            h_bf, WtQKV, qkvbias, QKVbuf, nullptr, M_TOT, QSTR, D, QSTR, 0, 0, 0);
        attn_kernel<<<dim3(80, NH), 256, 0, stream>>>(QKVbuf, q_mask, c_mask, attnout);
        // O proj -> fp32 delta
        mfma_gemm<0,1,0><<<dim3(M_TOT/128, D/128), 256, 0, stream>>>(
            attnout, WtO, bo + (size_t)l * D, deltaF, nullptr, M_TOT, D, D, D, 0, 0, 0);
        add_ln_kernel<<<M_TOT, 256, 0, stream>>>(h, deltaF, g1 + (size_t)l * D, be1 + (size_t)l * D, h_bf);
        // FFN1 + gelu -> bf16
        mfma_gemm<2,0,1><<<dim3(M_TOT/128, FF/128), 256, 0, stream>>>(
            h_bf, Wt1, bf1 + (size_t)l * FF, nullptr, ffn1_bf, M_TOT, FF, D, FF, 0, 0, 0);
        // FFN2 -> fp32 delta
        mfma_gemm<0,1,0><<<dim3(M_TOT/128, D/128), 256, 0, stream>>>(
            ffn1_bf, Wt2, bf2 + (size_t)l * D, deltaF, nullptr, M_TOT, D, FF, D, 0, 0, 0);
        add_ln_kernel<<<M_TOT, 256, 0, stream>>>(h, deltaF, g2 + (size_t)l * D, be2 + (size_t)l * D, h_bf);
    }

    // interaction: scores[b] = c_h[b] @ q_h[b]^T   (A = c rows, Bt = q rows, both bf16)
    mfma_gemm<0,1,0><<<dim3(CL/128, QL/128, NB), 256, 0, stream>>>(
        h_bf + (size_t)NB * QL * D, h_bf, nullptr, scores, nullptr,
        CL, QL, D, QL, (long)CL * D, (long)QL * D, (long)CL * QL);
    inter_softmax<<<dim3(CL, NB), 256, 0, stream>>>(scores);
    colmax_part<<<dim3(4, 16), 256, 0, stream>>>(scores, part);
    colmax_fin<<<4, 256, 0, stream>>>(part, tail);
    fc_kernel<<<1, 256, 0, stream>>>(tail, fcw, fcb, (float*)d_out);
}